// Round 6
// baseline (102996.948 us; speedup 1.0000x reference)
//
#include <hip/hip_runtime.h>

// ============================================================================
// Autoregressive 2-layer tanh RNN, B=256, T=512, IN=256, H=1024.
//
// Round-6: r5 numerics (proven: absmax 1.95e-3) + two structural fixes from
// the r5 counters (MfmaUtil 3%, FETCH 18 MB/step = weight refetch):
//  1. NO agent-acquire fence in the barrier (it buffer_inv'd all of L2 and
//     forced a full weight refetch every phase = 74 of 84 us/step).
//     Weights are READ-ONLY -> can never be stale -> stay hot in L2.
//     h-state (the only remotely-written data) is read via agent-scope
//     loads (__hip_atomic_load RELAXED/AGENT -> sc1, bypasses L1/L2, reads
//     the coherence point). Writer side keeps the agent-RELEASE fence
//     (writeback) so h reaches the coherence point before the counter bump.
//  2. Occupancy: 256 WGs x 512 thr (8 waves/CU on all 256 CUs, 2/SIMD) vs
//     64 WGs x 4 waves (1/SIMD on 1/4 of CUs).
//
// Tiling: layer tile 16x64 per WG (m0=(wg>>4)*16, n0=(wg&15)*64); 8 waves
// K-split 2048 -> 256 each (8 ksteps); wave = 1x4 frags of 16x16x32, 3
// products (a0b0+a0b1+a1b0, r5-proven). n-sharers co-XCD under %8 dispatch.
// fc tile 16x16, K=1024 8-way split. LDS only for the 8-way K-reduction.
// ============================================================================

#define B_SZ   256
#define IN_SZ  256
#define H_SZ   1024
#define NWG_M  256

typedef short v8s __attribute__((ext_vector_type(8)));
typedef float v4f __attribute__((ext_vector_type(4)));

// ---------------- bf16 helpers ----------------
__device__ __forceinline__ unsigned short bf16rne(float f) {
  unsigned x = __builtin_bit_cast(unsigned, f);
  return (unsigned short)((x + 0x7fffu + ((x >> 16) & 1u)) >> 16);
}
__device__ __forceinline__ float bf2f(unsigned short u) {
  unsigned x = ((unsigned)u) << 16;
  return __builtin_bit_cast(float, x);
}

// ---------------- barriers ----------------
// Release-only barrier (MFMA path): writeback L2 so h reaches the coherence
// point; readers use agent-scope loads, so NO cache invalidation is needed.
__device__ __forceinline__ void grid_barrier_rel(unsigned* cnt, int idx, unsigned nwg,
                                                 unsigned* abortf, unsigned* fail_s,
                                                 bool* dead) {
  __syncthreads();   // drains vmcnt of all waves' h stores
  if (*dead) return;
  if (threadIdx.x == 0) {
    __builtin_amdgcn_fence(__ATOMIC_RELEASE, "agent");   // L2 writeback
    __hip_atomic_fetch_add(&cnt[idx], 1u, __ATOMIC_RELAXED, __HIP_MEMORY_SCOPE_AGENT);
    unsigned f = 0, it = 0;
    while (__hip_atomic_load(&cnt[idx], __ATOMIC_RELAXED, __HIP_MEMORY_SCOPE_AGENT) < nwg) {
      __builtin_amdgcn_s_sleep(2);
      if ((++it & 1023u) == 0u) {
        if (__hip_atomic_load(abortf, __ATOMIC_RELAXED, __HIP_MEMORY_SCOPE_AGENT)) { f = 1; break; }
        if (it > 4000000u) {
          f = 1;
          __hip_atomic_store(abortf, 1u, __ATOMIC_RELAXED, __HIP_MEMORY_SCOPE_AGENT);
          break;
        }
      }
    }
    __builtin_amdgcn_fence(__ATOMIC_ACQUIRE, "workgroup");  // compiler/lgkm order only
    *fail_s = f;
  }
  __syncthreads();
  if (*fail_s) *dead = true;
  __builtin_amdgcn_sched_barrier(0);
}

// Original acquire barrier (f32 fallback path relies on L2 invalidation).
__device__ __forceinline__ void grid_barrier_acq(unsigned* cnt, int idx, unsigned nwg,
                                                 unsigned* abortf, unsigned* fail_s,
                                                 bool* dead) {
  __syncthreads();
  if (*dead) return;
  if (threadIdx.x == 0) {
    __builtin_amdgcn_fence(__ATOMIC_RELEASE, "agent");
    __hip_atomic_fetch_add(&cnt[idx], 1u, __ATOMIC_RELAXED, __HIP_MEMORY_SCOPE_AGENT);
    unsigned f = 0, it = 0;
    while (__hip_atomic_load(&cnt[idx], __ATOMIC_RELAXED, __HIP_MEMORY_SCOPE_AGENT) < nwg) {
      __builtin_amdgcn_s_sleep(2);
      if ((++it & 1023u) == 0u) {
        if (__hip_atomic_load(abortf, __ATOMIC_RELAXED, __HIP_MEMORY_SCOPE_AGENT)) { f = 1; break; }
        if (it > 4000000u) {
          f = 1;
          __hip_atomic_store(abortf, 1u, __ATOMIC_RELAXED, __HIP_MEMORY_SCOPE_AGENT);
          break;
        }
      }
    }
    __builtin_amdgcn_fence(__ATOMIC_ACQUIRE, "agent");
    *fail_s = f;
  }
  __syncthreads();
  if (*fail_s) *dead = true;
}

// ============================================================================
// MFMA path (r6)
// ============================================================================
struct MArgs {
  const float* y0;
  const unsigned short *B0p, *B1p, *W0p, *fcp;
  float *h0a, *h0b, *h1a, *h1b;
  const float *b_init, *b0p, *b1p, *fc_b;
  float* out;
  unsigned *cnt, *abortf;
  int T, nwg;
};

// acc[f] += A-slice @ B-slice^T over KS*32 of K. A: f32, read with
// agent-scope loads (fresh past L2), split2 in regs. B: pack2 records
// (16 shorts = [s0 x8][s1 x8] per 8-k block), plain loads (L2-hot).
template<int KS, int NF>
__device__ __forceinline__ void gemm_sc(
    const float* __restrict__ X, int lda, int m0, int ak0,
    const unsigned short* __restrict__ Bp, int kbtot, int n0, int bk0,
    int l15, int l4, v4f* acc) {
  const float* Ab = X + (long)(m0 + l15) * lda + ak0 + l4 * 8;
  const unsigned short* Bb =
      Bp + ((long)(n0 + l15) * kbtot + (bk0 >> 3) + l4) * 16;
#pragma unroll
  for (int ks = 0; ks < KS; ++ks) {
    float av[8];
#pragma unroll
    for (int j = 0; j < 8; ++j)
      av[j] = __hip_atomic_load((const float*)(Ab + ks * 32 + j),
                                __ATOMIC_RELAXED, __HIP_MEMORY_SCOPE_AGENT);
    v8s a0, a1;
#pragma unroll
    for (int j = 0; j < 8; ++j) {
      unsigned u = __builtin_bit_cast(unsigned, av[j]);
      float r = av[j] - __builtin_bit_cast(float, u & 0xFFFF0000u);
      a0[j] = (short)(u >> 16);
      a1[j] = (short)(__builtin_bit_cast(unsigned, r) >> 16);
    }
#pragma unroll
    for (int f = 0; f < NF; ++f) {
      const unsigned short* bp = Bb + ((long)f * 16 * kbtot + ks * 4) * 16;
      v8s b0 = *(const v8s*)bp;
      v8s b1 = *(const v8s*)(bp + 8);
      acc[f] = __builtin_amdgcn_mfma_f32_16x16x32_bf16(a0, b1, acc[f], 0, 0, 0);
      acc[f] = __builtin_amdgcn_mfma_f32_16x16x32_bf16(a1, b0, acc[f], 0, 0, 0);
      acc[f] = __builtin_amdgcn_mfma_f32_16x16x32_bf16(a0, b0, acc[f], 0, 0, 0);
    }
  }
}

#define RS 68   // reduction row stride (16-row x 64-col tile, 2-way banks max)

__global__ void __launch_bounds__(512, 2) rnn_mfma2_kernel(MArgs a) {
  __shared__ float red[8][16 * RS];   // 8 waves x 16x64 partials, ~34.8 KB
  __shared__ unsigned fail_s;
  bool dead = false;

  const int wg = blockIdx.x, tid = threadIdx.x;
  const int wv = tid >> 6, lane = tid & 63;
  const int l15 = lane & 15, l4 = lane >> 4;
  const int T = a.T, nwg = a.nwg;
  const long ldo = (long)T * IN_SZ;

  const int m0 = (wg >> 4) * 16;    // 16 m-blocks cover B=256
  const int n0 = (wg & 15) * 64;    // 16 n-blocks; same-n sharers co-XCD (%8)
  const int fn0 = (wg & 15) * 16;   // fc 16-col block

  float* h0p[2] = {a.h0a, a.h0b};
  float* h1p[2] = {a.h1a, a.h1b};

  v4f zero = {0.f, 0.f, 0.f, 0.f};
  int cur = 0, bar = 0;
  const int akw = (wv & 3) * 256;   // k-offset within the h operand
  const int bkw = wv * 256;         // k-offset within the packed B (K=2048)

  for (int t = 1; t < T; ++t) {
    const int nxt = cur ^ 1;

    // ================= Layer 0 =================
    {
      v4f acc[4] = {zero, zero, zero, zero};
      if (t == 1) {
        gemm_sc<1, 4>(a.y0, IN_SZ, m0, wv * 32, a.W0p, 32, n0, wv * 32,
                      l15, l4, acc);
      } else {
        const float* X = (wv < 4) ? h1p[cur] : h0p[cur];
        gemm_sc<8, 4>(X, H_SZ, m0, akw, a.B0p, 256, n0, bkw, l15, l4, acc);
      }
#pragma unroll
      for (int f = 0; f < 4; ++f)
#pragma unroll
        for (int j = 0; j < 4; ++j)
          red[wv][(l4 * 4 + j) * RS + f * 16 + l15] = acc[f][j];
      __syncthreads();
      const float* bias = (t == 1) ? a.b_init : a.b0p;
      float* dst = h0p[nxt];
#pragma unroll
      for (int e = 0; e < 2; ++e) {
        int idx = e * 512 + tid;
        int row = idx >> 6, col = idx & 63;
        int ro = row * RS + col;
        float v = red[0][ro] + red[1][ro] + red[2][ro] + red[3][ro] +
                  red[4][ro] + red[5][ro] + red[6][ro] + red[7][ro];
        dst[(long)(m0 + row) * H_SZ + n0 + col] = tanhf(v + bias[n0 + col]);
      }
    }
    grid_barrier_rel(a.cnt, bar++, (unsigned)nwg, a.abortf, &fail_s, &dead);

    // ================= Layer 1 =================
    {
      v4f acc[4] = {zero, zero, zero, zero};
      const float* X = (wv < 4) ? h0p[nxt] : h1p[cur];
      gemm_sc<8, 4>(X, H_SZ, m0, akw, a.B1p, 256, n0, bkw, l15, l4, acc);
#pragma unroll
      for (int f = 0; f < 4; ++f)
#pragma unroll
        for (int j = 0; j < 4; ++j)
          red[wv][(l4 * 4 + j) * RS + f * 16 + l15] = acc[f][j];
      __syncthreads();
      float* dst = h1p[nxt];
#pragma unroll
      for (int e = 0; e < 2; ++e) {
        int idx = e * 512 + tid;
        int row = idx >> 6, col = idx & 63;
        int ro = row * RS + col;
        float v = red[0][ro] + red[1][ro] + red[2][ro] + red[3][ro] +
                  red[4][ro] + red[5][ro] + red[6][ro] + red[7][ro];
        dst[(long)(m0 + row) * H_SZ + n0 + col] = tanhf(v + a.b1p[n0 + col]);
      }
    }
    grid_barrier_rel(a.cnt, bar++, (unsigned)nwg, a.abortf, &fail_s, &dead);

    // ================= FC: y_t (write-only, no barrier) =================
    {
      v4f facc = zero;
      gemm_sc<4, 1>(h1p[nxt], H_SZ, m0, wv * 128, a.fcp, 128, fn0, wv * 128,
                    l15, l4, &facc);
#pragma unroll
      for (int j = 0; j < 4; ++j)
        red[wv][(l4 * 4 + j) * 20 + l15] = facc[j];
      __syncthreads();
      if (tid < 256) {
        int row = tid >> 4, col = tid & 15;
        int ro = row * 20 + col;
        float v = red[0][ro] + red[1][ro] + red[2][ro] + red[3][ro] +
                  red[4][ro] + red[5][ro] + red[6][ro] + red[7][ro] +
                  a.fc_b[fn0 + col];
        a.out[(long)(m0 + row) * ldo + (long)t * IN_SZ + fn0 + col] = v;
      }
      __syncthreads();   // red free before next L0 writes
    }
    cur = nxt;
  }
}

// ---------------- precompute kernels (r5, proven) ----------------
__global__ void __launch_bounds__(256) pack2_kernel(
    const float* __restrict__ src, int R, int CB,
    unsigned short* __restrict__ dst, int KBtot, int kboff) {
  int i = blockIdx.x * 256 + threadIdx.x;
  if (i >= R * CB) return;
  int r = i / CB, cb = i - r * CB;
  const float* s = src + (long)r * (CB * 8) + cb * 8;
  unsigned short w[16];
#pragma unroll
  for (int e = 0; e < 8; ++e) {
    float v = s[e];
    unsigned short s0 = bf16rne(v);
    float rr = v - bf2f(s0);
    w[e] = s0;
    w[8 + e] = bf16rne(rr);
  }
  unsigned short* d = dst + ((long)r * KBtot + kboff + cb) * 16;
#pragma unroll
  for (int e = 0; e < 16; ++e) d[e] = w[e];
}

__global__ void __launch_bounds__(256) wc_pack2_kernel(
    const float* __restrict__ Wih0, const float* __restrict__ fcW,
    unsigned short* __restrict__ dst) {
  int i = blockIdx.x * 256 + threadIdx.x;   // 1024*128
  int r = i >> 7, jb = i & 127;
  float acc[8] = {0.f, 0.f, 0.f, 0.f, 0.f, 0.f, 0.f, 0.f};
  for (int c = 0; c < IN_SZ; ++c) {
    float w = Wih0[r * IN_SZ + c];
    const float* f = &fcW[c * H_SZ + jb * 8];
#pragma unroll
    for (int e = 0; e < 8; ++e) acc[e] = fmaf(w, f[e], acc[e]);
  }
  unsigned short* d = dst + ((long)r * 256 + jb) * 16;
#pragma unroll
  for (int e = 0; e < 8; ++e) {
    unsigned short s0 = bf16rne(acc[e]);
    float rr = acc[e] - bf2f(s0);
    d[e] = s0;
    d[8 + e] = bf16rne(rr);
  }
}

__global__ void bias_kernel(const float* bih0, const float* bhh0,
                            const float* bih1, const float* bhh1,
                            const float* __restrict__ Wih0,
                            const float* __restrict__ fcb,
                            float* b_init, float* b0p, float* b1p) {
  int i = blockIdx.x * 256 + threadIdx.x;
  if (i < H_SZ) {
    float sum = 0.f;
    for (int c = 0; c < IN_SZ; ++c) sum += Wih0[i * IN_SZ + c] * fcb[c];
    float bi = bih0[i] + bhh0[i];
    b_init[i] = bi;
    b0p[i] = bi + sum;
    b1p[i] = bih1[i] + bhh1[i];
  }
}

__global__ void y0copy_kernel(const float* __restrict__ y0,
                              float* __restrict__ out, int T) {
  int o = blockIdx.x * 256 + threadIdx.x;
  int b = o >> 6, c = (o & 63) << 2;
  *(float4*)&out[(size_t)b * T * IN_SZ + c] = *(const float4*)&y0[b * IN_SZ + c];
}

// ============================================================================
// Fallback f32 path (round-2, passing; uses the acquire barrier).
// ============================================================================
#define KC 128
#define KCP 132
#define LTILES 256
#define FTILES 64
struct alignas(16) SmemT { float A[16][KCP]; float W[64][KCP]; };
struct RnnArgs {
  const float *y0, *W_ih0, *W_hh0, *W_ih1, *W_hh1, *fc_W, *fc_b;
  const float *Wc, *b_init, *b0p, *b1p;
  float *h0a, *h0b, *h1a, *h1b, *out;
  unsigned *cnt, *abortf;
  int T, nwg, mode;
};
__device__ __forceinline__ void gemm_accum(const float* __restrict__ X, int ldx,
                                           const float* __restrict__ Wm, int K,
                                           int m0, int n0, int wv, int lane, int tid,
                                           SmemT& s, float* acc) {
  for (int kc = 0; kc < K; kc += KC) {
#pragma unroll
    for (int i = 0; i < 2; ++i) {
      int a = i * 256 + tid; int r = a >> 5, k = (a & 31) << 2;
      *(float4*)&s.A[r][k] = *(const float4*)&X[(size_t)(m0 + r) * ldx + kc + k];
    }
#pragma unroll
    for (int i = 0; i < 8; ++i) {
      int a = i * 256 + tid; int c = a >> 5, k = (a & 31) << 2;
      *(float4*)&s.W[c][k] = *(const float4*)&Wm[(size_t)(n0 + c) * K + kc + k];
    }
    __syncthreads();
#pragma unroll 4
    for (int k4 = 0; k4 < KC; k4 += 4) {
      float4 w4 = *(float4*)&s.W[lane][k4];
#pragma unroll
      for (int j = 0; j < 4; ++j) {
        float4 a4 = *(float4*)&s.A[wv + 4 * j][k4];
        acc[j] = fmaf(a4.x, w4.x, acc[j]); acc[j] = fmaf(a4.y, w4.y, acc[j]);
        acc[j] = fmaf(a4.z, w4.z, acc[j]); acc[j] = fmaf(a4.w, w4.w, acc[j]);
      }
    }
    __syncthreads();
  }
}
__global__ void __launch_bounds__(256) rnn_seq_kernel(RnnArgs a) {
  __shared__ SmemT s;
  __shared__ unsigned fail_s;
  bool dead = false;
  const int wg = blockIdx.x, tid = threadIdx.x;
  const int wv = tid >> 6, lane = tid & 63;
  const int T = a.T, nwg = a.nwg, mode = a.mode;
  const int ldo = T * IN_SZ;
  const float* h0[2] = {a.h0a, a.h0b};
  const float* h1[2] = {a.h1a, a.h1b};
  float* h0w[2] = {a.h0a, a.h0b};
  float* h1w[2] = {a.h1a, a.h1b};
  int cur = 0, bar = 0;
  for (int t = 1; t < T; ++t) {
    const int nxt = cur ^ 1;
    for (int tl = wg; tl < LTILES; tl += nwg) {
      const int m0 = (tl >> 4) << 4;
      const int n0 = (((tl & 7) << 1) | ((tl >> 3) & 1)) << 6;
      float acc[4] = {0.f, 0.f, 0.f, 0.f};
      const float* bias;
      if (t == 1) { gemm_accum(a.y0, IN_SZ, a.W_ih0, IN_SZ, m0, n0, wv, lane, tid, s, acc); bias = a.b_init; }
      else if (mode == 0) { gemm_accum(h1[cur], H_SZ, a.Wc, H_SZ, m0, n0, wv, lane, tid, s, acc); bias = a.b0p; }
      else { gemm_accum(a.out + (size_t)(t - 1) * IN_SZ, ldo, a.W_ih0, IN_SZ, m0, n0, wv, lane, tid, s, acc); bias = a.b_init; }
      gemm_accum(h0[cur], H_SZ, a.W_hh0, H_SZ, m0, n0, wv, lane, tid, s, acc);
      const float bv = bias[n0 + lane];
#pragma unroll
      for (int j = 0; j < 4; ++j)
        h0w[nxt][(size_t)(m0 + wv + 4 * j) * H_SZ + n0 + lane] = tanhf(acc[j] + bv);
    }
    grid_barrier_acq(a.cnt, bar++, (unsigned)nwg, a.abortf, &fail_s, &dead);
    for (int tl = wg; tl < LTILES; tl += nwg) {
      const int m0 = (tl >> 4) << 4;
      const int n0 = (((tl & 7) << 1) | ((tl >> 3) & 1)) << 6;
      float acc[4] = {0.f, 0.f, 0.f, 0.f};
      gemm_accum(h0[nxt], H_SZ, a.W_ih1, H_SZ, m0, n0, wv, lane, tid, s, acc);
      gemm_accum(h1[cur], H_SZ, a.W_hh1, H_SZ, m0, n0, wv, lane, tid, s, acc);
      const float bv = a.b1p[n0 + lane];
#pragma unroll
      for (int j = 0; j < 4; ++j)
        h1w[nxt][(size_t)(m0 + wv + 4 * j) * H_SZ + n0 + lane] = tanhf(acc[j] + bv);
    }
    grid_barrier_acq(a.cnt, bar++, (unsigned)nwg, a.abortf, &fail_s, &dead);
    for (int ft = wg; ft < FTILES; ft += nwg) {
      const int m0 = (ft >> 2) << 4;
      const int n0 = (ft & 3) << 6;
      float acc[4] = {0.f, 0.f, 0.f, 0.f};
      gemm_accum(h1[nxt], H_SZ, a.fc_W, H_SZ, m0, n0, wv, lane, tid, s, acc);
      const float bv = a.fc_b[n0 + lane];
#pragma unroll
      for (int j = 0; j < 4; ++j)
        a.out[(size_t)(m0 + wv + 4 * j) * ldo + (size_t)t * IN_SZ + n0 + lane] = acc[j] + bv;
    }
    if (mode == 1)
      grid_barrier_acq(a.cnt, bar++, (unsigned)nwg, a.abortf, &fail_s, &dead);
    cur = nxt;
  }
}
__global__ void __launch_bounds__(256) wc_kernel(const float* __restrict__ Wih0,
                                                 const float* __restrict__ fcW,
                                                 float* __restrict__ Wc) {
  int o = blockIdx.x * 256 + threadIdx.x;
  int i = o >> 8, j0 = (o & 255) << 2;
  float4 acc = {0.f, 0.f, 0.f, 0.f};
  for (int c = 0; c < IN_SZ; ++c) {
    float a = Wih0[i * IN_SZ + c];
    float4 f = *(const float4*)&fcW[c * H_SZ + j0];
    acc.x += a * f.x; acc.y += a * f.y; acc.z += a * f.z; acc.w += a * f.w;
  }
  *(float4*)&Wc[(size_t)i * H_SZ + j0] = acc;
}

// ============================================================================
extern "C" void kernel_launch(void* const* d_in, const int* in_sizes, int n_in,
                              void* d_out, int out_size, void* d_ws, size_t ws_size,
                              hipStream_t stream) {
  const float* y0    = (const float*)d_in[0];
  const float* W_ih0 = (const float*)d_in[2];
  const float* W_hh0 = (const float*)d_in[3];
  const float* b_ih0 = (const float*)d_in[4];
  const float* b_hh0 = (const float*)d_in[5];
  const float* W_ih1 = (const float*)d_in[6];
  const float* W_hh1 = (const float*)d_in[7];
  const float* b_ih1 = (const float*)d_in[8];
  const float* b_hh1 = (const float*)d_in[9];
  const float* fc_W  = (const float*)d_in[10];
  const float* fc_b  = (const float*)d_in[11];
  const int T = in_sizes[1];   // 512

  // ---- MFMA-path workspace (shorts, then floats) ----
  const long B0N = 1024L * 256 * 16;
  const long B1N = B0N;
  const long W0N = 1024L * 32 * 16;
  const long FCN = 256L * 128 * 16;
  const long hN  = (long)B_SZ * H_SZ;
  const size_t needNew = (2 * B0N + W0N + FCN) * 2 +
                         (4 * hN + 3 * H_SZ) * 4 + (2L * T + 8) * 4;

  int maxb = 0;
  hipError_t oe = hipOccupancyMaxActiveBlocksPerMultiprocessor(
      &maxb, rnn_mfma2_kernel, 512, 0);
  const bool tryNew = (ws_size >= needNew) && (oe == hipSuccess) && (maxb >= 1);

  if (tryNew) {
    unsigned short* ws16 = (unsigned short*)d_ws;
    unsigned short* B0p = ws16;  ws16 += B0N;
    unsigned short* B1p = ws16;  ws16 += B1N;
    unsigned short* W0p = ws16;  ws16 += W0N;
    unsigned short* fcp = ws16;  ws16 += FCN;
    float* wf  = (float*)ws16;
    float* h0a = wf;  wf += hN;
    float* h0b = wf;  wf += hN;
    float* h1a = wf;  wf += hN;
    float* h1b = wf;  wf += hN;
    float* b_init = wf;  wf += H_SZ;
    float* b0p = wf;     wf += H_SZ;
    float* b1p = wf;     wf += H_SZ;
    unsigned* cnt = (unsigned*)wf;
    unsigned* abortf = cnt + 2 * (size_t)T + 4;

    hipMemsetAsync(cnt, 0, (2 * (size_t)T + 5) * 4, stream);
    hipMemsetAsync(h0a, 0, hN * 4, stream);
    hipMemsetAsync(h1a, 0, hN * 4, stream);

    wc_pack2_kernel<<<512, 256, 0, stream>>>(W_ih0, fc_W, B0p);
    pack2_kernel<<<512, 256, 0, stream>>>(W_hh0, 1024, 128, B0p, 256, 128);
    pack2_kernel<<<512, 256, 0, stream>>>(W_ih1, 1024, 128, B1p, 256, 0);
    pack2_kernel<<<512, 256, 0, stream>>>(W_hh1, 1024, 128, B1p, 256, 128);
    pack2_kernel<<<128, 256, 0, stream>>>(W_ih0, 1024, 32, W0p, 32, 0);
    pack2_kernel<<<128, 256, 0, stream>>>(fc_W, 256, 128, fcp, 128, 0);
    bias_kernel<<<4, 256, 0, stream>>>(b_ih0, b_hh0, b_ih1, b_hh1, W_ih0, fc_b,
                                       b_init, b0p, b1p);
    y0copy_kernel<<<(B_SZ * IN_SZ / 4) / 256, 256, 0, stream>>>(y0, (float*)d_out, T);

    MArgs a;
    a.y0 = y0;
    a.B0p = B0p; a.B1p = B1p; a.W0p = W0p; a.fcp = fcp;
    a.h0a = h0a; a.h0b = h0b; a.h1a = h1a; a.h1b = h1b;
    a.b_init = b_init; a.b0p = b0p; a.b1p = b1p; a.fc_b = fc_b;
    a.out = (float*)d_out; a.cnt = cnt; a.abortf = abortf;
    a.T = T; a.nwg = NWG_M;
    void* kargs[] = {(void*)&a};
    hipError_t err = hipLaunchCooperativeKernel(rnn_mfma2_kernel, dim3(NWG_M),
                                                dim3(512), kargs, 0, stream);
    if (err == hipSuccess) return;
    // else fall through to f32 path (its precompute overwrites ws).
  }

  // ---------------- fallback f32 path ----------------
  const size_t hNf = (size_t)B_SZ * H_SZ;
  const size_t wcN = (size_t)H_SZ * H_SZ;
  const size_t cntN = 3 * (size_t)T + 8;
  const size_t need_full = (wcN + 4 * hNf + 3 * H_SZ + cntN) * 4;
  const int mode = (ws_size >= need_full) ? 0 : 1;

  float* ws = (float*)d_ws;
  float* Wc = nullptr;
  if (mode == 0) { Wc = ws; ws += wcN; }
  float* h0a = ws;  ws += hNf;
  float* h0b = ws;  ws += hNf;
  float* h1a = ws;  ws += hNf;
  float* h1b = ws;  ws += hNf;
  float* b_init = ws; ws += H_SZ;
  float* b0p = ws;  ws += H_SZ;
  float* b1p = ws;  ws += H_SZ;
  unsigned* cnt = (unsigned*)ws;
  unsigned* abortf = cnt + 3 * (size_t)T;

  hipMemsetAsync(cnt, 0, cntN * sizeof(unsigned), stream);
  hipMemsetAsync(h0a, 0, hNf * sizeof(float), stream);
  hipMemsetAsync(h1a, 0, hNf * sizeof(float), stream);
  if (mode == 0)
    wc_kernel<<<(H_SZ * H_SZ / 4) / 256, 256, 0, stream>>>(W_ih0, fc_W, Wc);
  bias_kernel<<<4, 256, 0, stream>>>(b_ih0, b_hh0, b_ih1, b_hh1, W_ih0, fc_b,
                                     b_init, b0p, b1p);
  y0copy_kernel<<<(B_SZ * IN_SZ / 4) / 256, 256, 0, stream>>>(y0, (float*)d_out, T);

  RnnArgs a;
  a.y0 = y0; a.W_ih0 = W_ih0; a.W_hh0 = W_hh0; a.W_ih1 = W_ih1; a.W_hh1 = W_hh1;
  a.fc_W = fc_W; a.fc_b = fc_b;
  a.Wc = Wc; a.b_init = b_init; a.b0p = b0p; a.b1p = b1p;
  a.h0a = h0a; a.h0b = h0b; a.h1a = h1a; a.h1b = h1b;
  a.out = (float*)d_out; a.cnt = cnt; a.abortf = abortf;
  a.T = T; a.nwg = 256; a.mode = mode;
  void* kargs[] = {(void*)&a};
  hipError_t err = hipLaunchCooperativeKernel(rnn_seq_kernel, dim3(256), dim3(256),
                                              kargs, 0, stream);
  int nwg = 256;
  while (err != hipSuccess && nwg > 16) {
    nwg >>= 1; a.nwg = nwg;
    err = hipLaunchCooperativeKernel(rnn_seq_kernel, dim3(nwg), dim3(256),
                                     kargs, 0, stream);
  }
}